// Round 8
// baseline (160.325 us; speedup 1.0000x reference)
//
#include <hip/hip_runtime.h>
#include <cstdint>

#define BATCH   8192
#define KDIM    256
#define HID     64
#define NODES   255
#define NPG     16    // nodes per block group

typedef unsigned short u16;
typedef unsigned int u32;
typedef short bf16x8 __attribute__((ext_vector_type(8)));
typedef float f32x16 __attribute__((ext_vector_type(16)));

// ---- helpers ---------------------------------------------------------------

__device__ __forceinline__ u32 f2bf(float f) {
  u32 u = __float_as_uint(f);
  return (u + 0x7FFFu + ((u >> 16) & 1u)) >> 16;
}

__device__ __forceinline__ void gld_lds16(const void* g, void* l) {
  // async global->LDS, 16B/lane; LDS dest = wave-uniform base + lane*16
  typedef __attribute__((address_space(1))) void* gp_t;
  typedef __attribute__((address_space(3))) void* lp_t;
  gp_t gp = reinterpret_cast<gp_t>(reinterpret_cast<uintptr_t>(g));
  lp_t lp = reinterpret_cast<lp_t>(static_cast<u32>(reinterpret_cast<uintptr_t>(l)));
  __builtin_amdgcn_global_load_lds(gp, lp, 16, 0, 0);
}

// ---- kernel 1: convert + pack ----------------------------------------------
// blocks [0,256):   x -> xpack (B-fragment granule order) via LDS transpose
// blocks [256,511): w1 -> w1pk, K-MAJOR granules: granule(node,kb,h) at
//                   node*2048 + kb*64 + h -> staging = identity copy; a-frag
//                   ds_reads = base + ks*2048 immediate offsets
// blocks [511,639): w2/b1 permute into MFMA C/D register order

#define NPRM 16320     // 255*64

__global__ __launch_bounds__(256) void cvt_kernel(
    const float* __restrict__ x, const float* __restrict__ w1,
    const float* __restrict__ b1, const float* __restrict__ w2,
    u16* __restrict__ xpack, u16* __restrict__ w1pk,
    float* __restrict__ b1p, float* __restrict__ w2p) {
  const int tid = threadIdx.x;
  const int blk = blockIdx.x;

  if (blk < 256) {
    __shared__ u16 sT[32 * 268];
    const float* xs = x + (size_t)blk * 32 * KDIM;
#pragma unroll
    for (int j = 0; j < 8; ++j) {
      int idx = j * 256 + tid;
      float4 v = ((const float4*)xs)[idx];
      int row = idx >> 6, f4 = idx & 63;
      *(u32*)&sT[row * 268 + f4 * 4]     = f2bf(v.x) | (f2bf(v.y) << 16);
      *(u32*)&sT[row * 268 + f4 * 4 + 2] = f2bf(v.z) | (f2bf(v.w) << 16);
    }
    __syncthreads();
#pragma unroll
    for (int j = 0; j < 4; ++j) {
      int d = j * 256 + tid;               // granule: ks*64 + hl*32 + l31
      int ks = d >> 6, hl = (d >> 5) & 1, l31 = d & 31;
      const u16* s8 = &sT[l31 * 268 + ks * 16 + hl * 8];
      u32 a = *(const u32*)s8, b = *(const u32*)(s8 + 2);
      u32 c = *(const u32*)(s8 + 4), e = *(const u32*)(s8 + 6);
      uint4 o = {a, b, c, e};
      ((uint4*)xpack)[(size_t)blk * 1024 + d] = o;
    }
  } else if (blk < 511) {
    __shared__ u16 sT[64 * 260];
    const int node = blk - 256;
    const float* src = w1 + (size_t)node * (HID * KDIM);
#pragma unroll
    for (int r = 0; r < 16; ++r) {
      int idx = r * 256 + tid;
      float4 v = ((const float4*)src)[idx];
      int h = idx >> 6, f4 = idx & 63;
      uint2 o;
      o.x = f2bf(v.x) | (f2bf(v.y) << 16);
      o.y = f2bf(v.z) | (f2bf(v.w) << 16);
      *(uint2*)&sT[h * 260 + f4 * 4] = o;
    }
    __syncthreads();
    u16* dst = w1pk + (size_t)node * (HID * KDIM);
#pragma unroll
    for (int r = 0; r < 8; ++r) {
      int g = r * 256 + tid;
      int kb = g >> 6, h = g & 63;
      const u16* s8 = &sT[h * 260 + kb * 8];
      uint2 lo = *(const uint2*)s8;
      uint2 hi = *(const uint2*)(s8 + 4);
      uint4 o = {lo.x, lo.y, hi.x, hi.y};
      ((uint4*)dst)[g] = o;
    }
  } else {
    int i2 = (blk - 511) * 256 + tid;
    if (i2 < 2 * NPRM) {
      int a = i2 >= NPRM;
      int j = a ? i2 - NPRM : i2;
      int reg = j & 15, rt = (j >> 4) & 1, hl = (j >> 5) & 1, node = j >> 6;
      int h = rt * 32 + (reg & 3) + 8 * (reg >> 2) + 4 * hl;
      float v = (a ? b1 : w2)[node * 64 + h];
      (a ? b1p : w2p)[j] = v;
    }
  }
}

// ---- kernel 2: fused MLP ---------------------------------------------------
// Block = 128 batch cols x 1 node (looped x16). Wave (ch=wv>>1, rt=wv&1):
// 64 cols x 32 hidden. xf PINNED in 128 VGPRs via empty inline asm (R7 showed
// the compiler otherwise re-loads them from L2 every iter: VGPR_Count=104).

__global__ __launch_bounds__(256, 2) void fused_mlp_kernel(
    const u16* __restrict__ xpack,  // packed B-frag granules
    const u16* __restrict__ w1pk,   // [256(pad)][32 kb][64 h] granules
    const float* __restrict__ b1p,  // [255][2 hl][2 rt][16] permuted
    const float* __restrict__ w2p,  // [255][2 hl][2 rt][16] permuted
    const float* __restrict__ b2,   // [255]
    float* __restrict__ no_t)       // [255][8192] node_outputs transposed
{
  __shared__ __align__(16) u16 sW[2][HID * KDIM];  // 2 x 32 KB, K-major
  __shared__ __align__(16) float sW2[NPG * 64];    // 4 KB
  __shared__ __align__(16) float sB1[NPG * 64];    // 4 KB
  __shared__ float sP[2][4][64];                   // parity x wave x col

  const int tid  = threadIdx.x;
  const int lane = tid & 63;
  const int wv   = tid >> 6;
  const int l31  = lane & 31;
  const int hl   = lane >> 5;
  const int rt   = wv & 1;
  const int ch   = wv >> 1;
  const int nbase = blockIdx.y * NPG;

  auto stage = [&](int node, int buf) {
    const u16* base = w1pk + (size_t)node * (HID * KDIM);
    char* lb = (char*)(&sW[buf][0]);
#pragma unroll
    for (int j = 0; j < 8; ++j) {
      int s = j * 256 + tid;
      gld_lds16(base + s * 8, lb + s * 16);  // identity copy, zero addr math
    }
  };

  stage(nbase, 0);
  gld_lds16(w2p + (size_t)nbase * 64 + tid * 4, (char*)sW2 + tid * 16);
  gld_lds16(b1p + (size_t)nbase * 64 + tid * 4, (char*)sB1 + tid * 16);

  // ---- x fragments: 2 col-tiles of 32 x 16 ks, coalesced; then PIN ----
  const int ctile0 = blockIdx.x * 4 + ch * 2;
  bf16x8 xf[2][16];
#pragma unroll
  for (int ct = 0; ct < 2; ++ct) {
    const u16* src = xpack + ((size_t)(ctile0 + ct) * 16) * 512 + lane * 8;
#pragma unroll
    for (int ks = 0; ks < 16; ++ks)
      xf[ct][ks] = *(const bf16x8*)(src + ks * 512);
  }
  // make xf opaque register values: compiler can no longer rematerialize
  // them by re-loading from global inside the node loop
#pragma unroll
  for (int ct = 0; ct < 2; ++ct)
#pragma unroll
    for (int ks = 0; ks < 16; ++ks)
      asm volatile("" : "+v"(xf[ct][ks]));

  // lane's a-frag base: granule (kb = ks*2+hl, h = rt*32+l31)
  const u32 abase = (u32)(hl * 64 + rt * 32 + l31) * 16u;

  __syncthreads();  // drains staging vmcnt
  int buf = 0, par = 0;

  for (int i = 0; i < NPG; ++i) {
    const int node = nbase + i;
    if (i + 1 < NPG) stage(node + 1, buf ^ 1);

    f32x16 acc0 = (f32x16){0}, acc1 = (f32x16){0};
    const char* sw = (const char*)&sW[buf][0] + abase;
#pragma unroll
    for (int ks = 0; ks < 16; ++ks) {
      bf16x8 a = *(const bf16x8*)(sw + ks * 2048);   // immediate offsets
      acc0 = __builtin_amdgcn_mfma_f32_32x32x16_bf16(a, xf[0][ks], acc0, 0, 0, 0);
      acc1 = __builtin_amdgcn_mfma_f32_32x32x16_bf16(a, xf[1][ks], acc1, 0, 0, 0);
    }

    // ---- epilogue: partial logit over this wave's 32 hidden rows ----
    float p0 = 0.f, p1 = 0.f;
#pragma unroll
    for (int qd = 0; qd < 4; ++qd) {
      int o = i * 64 + hl * 32 + rt * 16 + qd * 4;
      float4 wq = *(const float4*)&sW2[o];
      float4 bq = *(const float4*)&sB1[o];
#pragma unroll
      for (int e = 0; e < 4; ++e) {
        float w = (&wq.x)[e];
        float bb = (&bq.x)[e];
        p0 += fmaxf(acc0[qd * 4 + e] + bb, 0.f) * w;
        p1 += fmaxf(acc1[qd * 4 + e] + bb, 0.f) * w;
      }
    }
    p0 += __shfl_xor(p0, 32);
    p1 += __shfl_xor(p1, 32);
    if (hl == 0) {
      sP[par][wv][l31]      = p0;   // col ch*64 + l31
      sP[par][wv][32 + l31] = p1;   // col ch*64 + 32 + l31
    }

    __syncthreads();  // sP visible; staged buf^1 drained; sW[buf] readers done

    if (tid < 128 && node < NODES) {
      int chh = tid >> 6, c = tid & 63;
      float logit = sP[par][chh * 2][c] + sP[par][chh * 2 + 1][c] + b2[node];
      float sig = 1.0f / (1.0f + expf(-logit));
      no_t[(size_t)node * BATCH + blockIdx.x * 128 + tid] = sig;
    }

    buf ^= 1;
    par ^= 1;  // next iter's sP writes go to the other buffer (no race)
  }
}

// ---- kernel 3: soft-decision-tree traversal --------------------------------

__global__ __launch_bounds__(256) void tree_kernel(
    const float* __restrict__ no_t,  // [255][8192]
    const float* __restrict__ leaf,  // [256]
    float* __restrict__ out)
{
  __shared__ float p[16][257];

  const int tid = threadIdx.x;
  const int bbase = blockIdx.x * 16;
  const int wave = tid >> 6;
  const int lane = tid & 63;

  for (int i = tid; i < NODES * 16; i += 256) {
    int n = i >> 4, r = i & 15;
    p[r][n] = no_t[(size_t)n * BATCH + bbase + r];
  }
  __syncthreads();

  float4 lw = ((const float4*)leaf)[lane];

  float* h_out  = out;
  float* pp_out = out + 8192;                            // [8192][256]
  float* no_out = out + 8192 + 8192 * 256;               // [8192][255]
  float* nr_out = out + 8192 + 8192 * 256 + 8192 * (size_t)NODES;  // [8192][255]

  for (int j = 0; j < 4; ++j) {
    const int r = wave * 4 + j;
    const int b = bbase + r;
    const float* pr = p[r];
    float* nr_b = nr_out + (size_t)b * NODES;

    float rc = 1.f;
#pragma unroll
    for (int L = 0; L < 6; ++L) {
      if (lane < (1 << L)) nr_b[(1 << L) - 1 + lane] = rc;
      float par = __shfl(rc, lane >> 1);
      float pv = pr[(1 << L) - 1 + (lane >> 1)];
      rc = par * ((lane & 1) ? pv : (1.f - pv));
    }
    nr_b[63 + lane] = rc;
    float p6 = pr[63 + lane];
    float r7a = rc * (1.f - p6), r7b = rc * p6;
    nr_b[127 + 2 * lane]     = r7a;
    nr_b[127 + 2 * lane + 1] = r7b;
    float p7a = pr[127 + 2 * lane], p7b = pr[127 + 2 * lane + 1];
    float4 pp;
    pp.x = r7a * (1.f - p7a);
    pp.y = r7a * p7a;
    pp.z = r7b * (1.f - p7b);
    pp.w = r7b * p7b;
    ((float4*)(pp_out + (size_t)b * 256))[lane] = pp;

    float* no_b = no_out + (size_t)b * NODES;
#pragma unroll
    for (int k = 0; k < 4; ++k) {
      int n = lane + 64 * k;
      if (n < NODES) no_b[n] = pr[n];
    }

    float hacc = pp.x * lw.x + pp.y * lw.y + pp.z * lw.z + pp.w * lw.w;
    hacc += __shfl_xor(hacc, 1);
    hacc += __shfl_xor(hacc, 2);
    hacc += __shfl_xor(hacc, 4);
    hacc += __shfl_xor(hacc, 8);
    hacc += __shfl_xor(hacc, 16);
    hacc += __shfl_xor(hacc, 32);
    if (lane == 0) h_out[b] = hacc;
  }
}

// ---- launcher --------------------------------------------------------------

extern "C" void kernel_launch(void* const* d_in, const int* in_sizes, int n_in,
                              void* d_out, int out_size, void* d_ws, size_t ws_size,
                              hipStream_t stream) {
  const float* x    = (const float*)d_in[0];
  const float* w1   = (const float*)d_in[1];
  const float* b1   = (const float*)d_in[2];
  const float* w2   = (const float*)d_in[3];
  const float* b2   = (const float*)d_in[4];
  const float* leaf = (const float*)d_in[5];
  float* out = (float*)d_out;

  // ws: xpack 4MB | w1pk 8MB (256-node pad; node 255 poison-but-finite) |
  //     w2p 64KB | b1p 64KB | no_t 8MB
  char* ws = (char*)d_ws;
  u16*   xpack = (u16*)ws;
  u16*   w1pk  = (u16*)(ws + (size_t)4194304);
  float* w2p   = (float*)(ws + (size_t)12582912);
  float* b1p   = (float*)(ws + (size_t)12648192);
  float* no_t  = (float*)(ws + (size_t)12713472);

  cvt_kernel<<<639, 256, 0, stream>>>(x, w1, b1, w2, xpack, w1pk, b1p, w2p);

  dim3 g(64, 16);  // 64 col-blocks (128 cols) x 16 node-groups = 1024 blocks
  fused_mlp_kernel<<<g, 256, 0, stream>>>(xpack, w1pk, b1p, w2p, b2, no_t);

  tree_kernel<<<BATCH / 16, 256, 0, stream>>>(no_t, leaf, out);
}

// Round 9
// 155.652 us; speedup vs baseline: 1.0300x; 1.0300x over previous
//
#include <hip/hip_runtime.h>
#include <cstdint>

#define BATCH   8192
#define KDIM    256
#define HID     64
#define NODES   255
#define NPG     16    // nodes per block group

typedef unsigned short u16;
typedef unsigned int u32;
typedef short bf16x8 __attribute__((ext_vector_type(8)));
typedef float f32x16 __attribute__((ext_vector_type(16)));

// ---- helpers ---------------------------------------------------------------

__device__ __forceinline__ u32 f2bf(float f) {
  u32 u = __float_as_uint(f);
  return (u + 0x7FFFu + ((u >> 16) & 1u)) >> 16;
}

__device__ __forceinline__ void gld_lds16(const void* g, void* l) {
  // async global->LDS, 16B/lane; LDS dest = wave-uniform base + lane*16
  typedef __attribute__((address_space(1))) void* gp_t;
  typedef __attribute__((address_space(3))) void* lp_t;
  gp_t gp = reinterpret_cast<gp_t>(reinterpret_cast<uintptr_t>(g));
  lp_t lp = reinterpret_cast<lp_t>(static_cast<u32>(reinterpret_cast<uintptr_t>(l)));
  __builtin_amdgcn_global_load_lds(gp, lp, 16, 0, 0);
}

// ---- kernel 1: convert + pack ----------------------------------------------
// blocks [0,256):   x -> xpack (B-fragment granule order) via LDS transpose
// blocks [256,511): w1 -> w1pk, K-MAJOR granules: granule(node,kb,h) at
//                   node*2048 + kb*64 + h -> staging = identity copy
// blocks [511,639): w2/b1 permute into MFMA C/D register order

#define NPRM 16320     // 255*64

__global__ __launch_bounds__(256) void cvt_kernel(
    const float* __restrict__ x, const float* __restrict__ w1,
    const float* __restrict__ b1, const float* __restrict__ w2,
    u16* __restrict__ xpack, u16* __restrict__ w1pk,
    float* __restrict__ b1p, float* __restrict__ w2p) {
  const int tid = threadIdx.x;
  const int blk = blockIdx.x;

  if (blk < 256) {
    __shared__ u16 sT[32 * 268];
    const float* xs = x + (size_t)blk * 32 * KDIM;
#pragma unroll
    for (int j = 0; j < 8; ++j) {
      int idx = j * 256 + tid;
      float4 v = ((const float4*)xs)[idx];
      int row = idx >> 6, f4 = idx & 63;
      *(u32*)&sT[row * 268 + f4 * 4]     = f2bf(v.x) | (f2bf(v.y) << 16);
      *(u32*)&sT[row * 268 + f4 * 4 + 2] = f2bf(v.z) | (f2bf(v.w) << 16);
    }
    __syncthreads();
#pragma unroll
    for (int j = 0; j < 4; ++j) {
      int d = j * 256 + tid;               // granule: ks*64 + hl*32 + l31
      int ks = d >> 6, hl = (d >> 5) & 1, l31 = d & 31;
      const u16* s8 = &sT[l31 * 268 + ks * 16 + hl * 8];
      u32 a = *(const u32*)s8, b = *(const u32*)(s8 + 2);
      u32 c = *(const u32*)(s8 + 4), e = *(const u32*)(s8 + 6);
      uint4 o = {a, b, c, e};
      ((uint4*)xpack)[(size_t)blk * 1024 + d] = o;
    }
  } else if (blk < 511) {
    __shared__ u16 sT[64 * 260];
    const int node = blk - 256;
    const float* src = w1 + (size_t)node * (HID * KDIM);
#pragma unroll
    for (int r = 0; r < 16; ++r) {
      int idx = r * 256 + tid;
      float4 v = ((const float4*)src)[idx];
      int h = idx >> 6, f4 = idx & 63;
      uint2 o;
      o.x = f2bf(v.x) | (f2bf(v.y) << 16);
      o.y = f2bf(v.z) | (f2bf(v.w) << 16);
      *(uint2*)&sT[h * 260 + f4 * 4] = o;
    }
    __syncthreads();
    u16* dst = w1pk + (size_t)node * (HID * KDIM);
#pragma unroll
    for (int r = 0; r < 8; ++r) {
      int g = r * 256 + tid;
      int kb = g >> 6, h = g & 63;
      const u16* s8 = &sT[h * 260 + kb * 8];
      uint2 lo = *(const uint2*)s8;
      uint2 hi = *(const uint2*)(s8 + 4);
      uint4 o = {lo.x, lo.y, hi.x, hi.y};
      ((uint4*)dst)[g] = o;
    }
  } else {
    int i2 = (blk - 511) * 256 + tid;
    if (i2 < 2 * NPRM) {
      int a = i2 >= NPRM;
      int j = a ? i2 - NPRM : i2;
      int reg = j & 15, rt = (j >> 4) & 1, hl = (j >> 5) & 1, node = j >> 6;
      int h = rt * 32 + (reg & 3) + 8 * (reg >> 2) + 4 * hl;
      float v = (a ? b1 : w2)[node * 64 + h];
      (a ? b1p : w2p)[j] = v;
    }
  }
}

// ---- kernel 2: fused MLP ---------------------------------------------------
// Block = 128 batch cols x 1 node (looped x16). Wave (ch=wv>>1, rt=wv&1):
// 64 cols x 32 hidden. HALF-NODE dbuf staging (2x16KB) -> LDS 43KB/block ->
// 3 blocks/CU (R8 ran 2: 38% MfmaUtil == 2x1034/5470 cyc exactly; occupancy
// was the limiter and LDS was what capped it).

__global__ __launch_bounds__(256, 2) void fused_mlp_kernel(
    const u16* __restrict__ xpack,  // packed B-frag granules
    const u16* __restrict__ w1pk,   // [256(pad)][32 kb][64 h] granules
    const float* __restrict__ b1p,  // [255][2 hl][2 rt][16] permuted
    const float* __restrict__ w2p,  // [255][2 hl][2 rt][16] permuted
    const float* __restrict__ b2,   // [255]
    float* __restrict__ no_t)       // [255][8192] node_outputs transposed
{
  __shared__ __align__(16) u16 sW[2][1024 * 8];    // 2 x 16 KB (half node)
  __shared__ __align__(16) float sW2[NPG * 64];    // 4 KB
  __shared__ __align__(16) float sB1[NPG * 64];    // 4 KB
  __shared__ float sP[2][4][64];                   // parity x wave x col

  const int tid  = threadIdx.x;
  const int lane = tid & 63;
  const int wv   = tid >> 6;
  const int l31  = lane & 31;
  const int hl   = lane >> 5;
  const int rt   = wv & 1;
  const int ch   = wv >> 1;
  const int nbase = blockIdx.y * NPG;

  // stage one half-node (1024 granules = 16 KB): identity copy
  auto stage_half = [&](int halfIdx, int buf) {
    const u16* base = w1pk + (size_t)halfIdx * (1024 * 8);
    char* lb = (char*)(&sW[buf][0]);
#pragma unroll
    for (int j = 0; j < 4; ++j) {
      int s = j * 256 + tid;
      gld_lds16(base + s * 8, lb + s * 16);
    }
  };

  stage_half(nbase * 2, 0);
  gld_lds16(w2p + (size_t)nbase * 64 + tid * 4, (char*)sW2 + tid * 16);
  gld_lds16(b1p + (size_t)nbase * 64 + tid * 4, (char*)sB1 + tid * 16);

  // ---- x fragments: 2 col-tiles of 32 x 16 ks, coalesced ----
  const int ctile0 = blockIdx.x * 4 + ch * 2;
  bf16x8 xf[2][16];
#pragma unroll
  for (int ct = 0; ct < 2; ++ct) {
    const u16* src = xpack + ((size_t)(ctile0 + ct) * 16) * 512 + lane * 8;
#pragma unroll
    for (int ks = 0; ks < 16; ++ks)
      xf[ct][ks] = *(const bf16x8*)(src + ks * 512);
  }

  // lane's a-frag base within a half-buffer: granule (kb_l = ks*2+hl, h = rt*32+l31)
  const u32 abase = (u32)(hl * 64 + rt * 32 + l31) * 16u;

  __syncthreads();  // drains staging vmcnt
  int buf = 0, par = 0;

  for (int i = 0; i < NPG; ++i) {
    const int node = nbase + i;
    f32x16 acc0 = (f32x16){0}, acc1 = (f32x16){0};

#pragma unroll
    for (int h = 0; h < 2; ++h) {
      int nexth = i * 2 + h + 1;
      if (nexth < NPG * 2) stage_half(nbase * 2 + nexth, buf ^ 1);

      const char* sw = (const char*)&sW[buf][0] + abase;
#pragma unroll
      for (int ks = 0; ks < 8; ++ks) {
        bf16x8 a = *(const bf16x8*)(sw + ks * 2048);   // immediate offsets
        acc0 = __builtin_amdgcn_mfma_f32_32x32x16_bf16(a, xf[0][h * 8 + ks], acc0, 0, 0, 0);
        acc1 = __builtin_amdgcn_mfma_f32_32x32x16_bf16(a, xf[1][h * 8 + ks], acc1, 0, 0, 0);
      }
      if (h == 0) __syncthreads();  // next-half staged + buf readers done
      buf ^= 1;
    }

    // ---- epilogue: partial logit over this wave's 32 hidden rows ----
    float p0 = 0.f, p1 = 0.f;
#pragma unroll
    for (int qd = 0; qd < 4; ++qd) {
      int o = i * 64 + hl * 32 + rt * 16 + qd * 4;
      float4 wq = *(const float4*)&sW2[o];
      float4 bq = *(const float4*)&sB1[o];
#pragma unroll
      for (int e = 0; e < 4; ++e) {
        float w = (&wq.x)[e];
        float bb = (&bq.x)[e];
        p0 += fmaxf(acc0[qd * 4 + e] + bb, 0.f) * w;
        p1 += fmaxf(acc1[qd * 4 + e] + bb, 0.f) * w;
      }
    }
    p0 += __shfl_xor(p0, 32);
    p1 += __shfl_xor(p1, 32);
    if (hl == 0) {
      sP[par][wv][l31]      = p0;   // col ch*64 + l31
      sP[par][wv][32 + l31] = p1;   // col ch*64 + 32 + l31
    }

    __syncthreads();  // sP visible; next half-stage drained; buf readers done

    if (tid < 128 && node < NODES) {
      int chh = tid >> 6, c = tid & 63;
      float logit = sP[par][chh * 2][c] + sP[par][chh * 2 + 1][c] + b2[node];
      float sig = 1.0f / (1.0f + expf(-logit));
      no_t[(size_t)node * BATCH + blockIdx.x * 128 + tid] = sig;
    }

    par ^= 1;  // next iter's sP writes go to the other buffer (no race)
  }
}

// ---- kernel 3: soft-decision-tree traversal --------------------------------

__global__ __launch_bounds__(256) void tree_kernel(
    const float* __restrict__ no_t,  // [255][8192]
    const float* __restrict__ leaf,  // [256]
    float* __restrict__ out)
{
  __shared__ float p[16][257];

  const int tid = threadIdx.x;
  const int bbase = blockIdx.x * 16;
  const int wave = tid >> 6;
  const int lane = tid & 63;

  for (int i = tid; i < NODES * 16; i += 256) {
    int n = i >> 4, r = i & 15;
    p[r][n] = no_t[(size_t)n * BATCH + bbase + r];
  }
  __syncthreads();

  float4 lw = ((const float4*)leaf)[lane];

  float* h_out  = out;
  float* pp_out = out + 8192;                            // [8192][256]
  float* no_out = out + 8192 + 8192 * 256;               // [8192][255]
  float* nr_out = out + 8192 + 8192 * 256 + 8192 * (size_t)NODES;  // [8192][255]

  for (int j = 0; j < 4; ++j) {
    const int r = wave * 4 + j;
    const int b = bbase + r;
    const float* pr = p[r];
    float* nr_b = nr_out + (size_t)b * NODES;

    float rc = 1.f;
#pragma unroll
    for (int L = 0; L < 6; ++L) {
      if (lane < (1 << L)) nr_b[(1 << L) - 1 + lane] = rc;
      float par = __shfl(rc, lane >> 1);
      float pv = pr[(1 << L) - 1 + (lane >> 1)];
      rc = par * ((lane & 1) ? pv : (1.f - pv));
    }
    nr_b[63 + lane] = rc;
    float p6 = pr[63 + lane];
    float r7a = rc * (1.f - p6), r7b = rc * p6;
    nr_b[127 + 2 * lane]     = r7a;
    nr_b[127 + 2 * lane + 1] = r7b;
    float p7a = pr[127 + 2 * lane], p7b = pr[127 + 2 * lane + 1];
    float4 pp;
    pp.x = r7a * (1.f - p7a);
    pp.y = r7a * p7a;
    pp.z = r7b * (1.f - p7b);
    pp.w = r7b * p7b;
    ((float4*)(pp_out + (size_t)b * 256))[lane] = pp;

    float* no_b = no_out + (size_t)b * NODES;
#pragma unroll
    for (int k = 0; k < 4; ++k) {
      int n = lane + 64 * k;
      if (n < NODES) no_b[n] = pr[n];
    }

    float hacc = pp.x * lw.x + pp.y * lw.y + pp.z * lw.z + pp.w * lw.w;
    hacc += __shfl_xor(hacc, 1);
    hacc += __shfl_xor(hacc, 2);
    hacc += __shfl_xor(hacc, 4);
    hacc += __shfl_xor(hacc, 8);
    hacc += __shfl_xor(hacc, 16);
    hacc += __shfl_xor(hacc, 32);
    if (lane == 0) h_out[b] = hacc;
  }
}

// ---- launcher --------------------------------------------------------------

extern "C" void kernel_launch(void* const* d_in, const int* in_sizes, int n_in,
                              void* d_out, int out_size, void* d_ws, size_t ws_size,
                              hipStream_t stream) {
  const float* x    = (const float*)d_in[0];
  const float* w1   = (const float*)d_in[1];
  const float* b1   = (const float*)d_in[2];
  const float* w2   = (const float*)d_in[3];
  const float* b2   = (const float*)d_in[4];
  const float* leaf = (const float*)d_in[5];
  float* out = (float*)d_out;

  // ws: xpack 4MB | w1pk 8MB (256-node pad; node 255 poison-but-finite) |
  //     w2p 64KB | b1p 64KB | no_t 8MB
  char* ws = (char*)d_ws;
  u16*   xpack = (u16*)ws;
  u16*   w1pk  = (u16*)(ws + (size_t)4194304);
  float* w2p   = (float*)(ws + (size_t)12582912);
  float* b1p   = (float*)(ws + (size_t)12648192);
  float* no_t  = (float*)(ws + (size_t)12713472);

  cvt_kernel<<<639, 256, 0, stream>>>(x, w1, b1, w2, xpack, w1pk, b1p, w2p);

  dim3 g(64, 16);  // 64 col-blocks (128 cols) x 16 node-groups = 1024 blocks
  fused_mlp_kernel<<<g, 256, 0, stream>>>(xpack, w1pk, b1p, w2p, b2, no_t);

  tree_kernel<<<BATCH / 16, 256, 0, stream>>>(no_t, leaf, out);
}